// Round 1
// baseline (241.027 us; speedup 1.0000x reference)
//
#include <hip/hip_runtime.h>

// MFMA fragment types per cdna_hip_programming.md §3 (compile-verified on gfx950)
typedef __attribute__((ext_vector_type(8))) short bf16x8;
typedef __attribute__((ext_vector_type(4))) float f32x4;

__device__ __forceinline__ unsigned short f2bf(float f) {
    union { float f; unsigned u; } v; v.f = f;
    return (unsigned short)((v.u + 0x7FFFu + ((v.u >> 16) & 1u)) >> 16);  // RNE
}

// ---------------- Kernel 0: weight transpose + bf16 cast ----------------
// wt[n][k] = W[k][n];  n in [0,32): Wf, [32,64): Wg, [64,320): Wh
__global__ __launch_bounds__(256) void k_wt(const float* __restrict__ kf,
                                            const float* __restrict__ kg,
                                            const float* __restrict__ kh,
                                            unsigned short* __restrict__ wt) {
    int n = blockIdx.x, t = threadIdx.x;
    const float* src; int stride, col;
    if (n < 32)      { src = kf; stride = 32;  col = n; }
    else if (n < 64) { src = kg; stride = 32;  col = n - 32; }
    else             { src = kh; stride = 256; col = n - 64; }
    wt[n * 256 + t] = f2bf(src[t * stride + col]);
}

// ---------------- Kernel 1: f,g projections -----------------------------
// M=16384 rows (64/WG), N=64 (f||g), K=256 (two 128-chunks staged in LDS)
__global__ __launch_bounds__(256) void k_proj_fg(const float* __restrict__ x,
                                                 const unsigned short* __restrict__ wt,
                                                 unsigned short* __restrict__ f,
                                                 unsigned short* __restrict__ g) {
    __shared__ unsigned short xs[64][136];  // 64 rows x 128 k (+8 pad)
    __shared__ unsigned short ws[64][136];
    int t = threadIdx.x, rb = blockIdx.x;
    int w = t >> 6, lane = t & 63, q = lane >> 4, n15 = lane & 15;
    f32x4 acc[4];
#pragma unroll
    for (int i = 0; i < 4; ++i) acc[i] = (f32x4){0.f, 0.f, 0.f, 0.f};

    for (int kh2 = 0; kh2 < 2; ++kh2) {
        __syncthreads();
#pragma unroll
        for (int i = 0; i < 8; ++i) {            // x tile: 64x128 fp32 -> bf16
            int lin = i * 256 + t, row = lin >> 5, c4 = lin & 31;
            float4 v = *(const float4*)&x[(rb * 64 + row) * 256 + kh2 * 128 + c4 * 4];
            ushort4 o; o.x = f2bf(v.x); o.y = f2bf(v.y); o.z = f2bf(v.z); o.w = f2bf(v.w);
            *(ushort4*)&xs[row][c4 * 4] = o;
        }
#pragma unroll
        for (int i = 0; i < 4; ++i) {            // Wt rows 0..63, this k-chunk
            int lin = i * 256 + t, row = lin >> 4, s = lin & 15;
            *(uint4*)&ws[row][s * 8] = *(const uint4*)&wt[row * 256 + kh2 * 128 + s * 8];
        }
        __syncthreads();
#pragma unroll
        for (int kk = 0; kk < 4; ++kk) {
            bf16x8 a = *(const bf16x8*)&xs[w * 16 + n15][kk * 32 + q * 8];
#pragma unroll
            for (int nt = 0; nt < 4; ++nt) {
                bf16x8 b = *(const bf16x8*)&ws[nt * 16 + n15][kk * 32 + q * 8];
                acc[nt] = __builtin_amdgcn_mfma_f32_16x16x32_bf16(a, b, acc[nt], 0, 0, 0);
            }
        }
    }
#pragma unroll
    for (int nt = 0; nt < 4; ++nt)
#pragma unroll
        for (int r = 0; r < 4; ++r) {
            int grow = rb * 64 + w * 16 + q * 4 + r;   // C/D: row=(lane>>4)*4+reg
            int col = nt * 16 + n15;                   //      col=lane&15
            unsigned short v = f2bf(acc[nt][r]);
            if (col < 32) f[grow * 32 + col] = v;
            else          g[grow * 32 + (col - 32)] = v;
        }
}

// ---------------- Kernel 2: h projection, stored transposed -------------
// D[m=ch][n=row] = sum_k Wh^T[ch][k] * x[row][k]  -> hT[b][ch][n] bf16
__global__ __launch_bounds__(256) void k_proj_h(const float* __restrict__ x,
                                                const unsigned short* __restrict__ wt,
                                                unsigned short* __restrict__ hT) {
    __shared__ unsigned short wa[64][136];
    __shared__ unsigned short xs[64][136];
    int t = threadIdx.x;
    int ct = blockIdx.x & 3, rt = blockIdx.x >> 2;
    int chbase = ct * 64;
    int w = t >> 6, lane = t & 63, q = lane >> 4, n15 = lane & 15;
    int b = rt >> 6, nbase = (rt & 63) * 64;
    f32x4 acc[4];
#pragma unroll
    for (int i = 0; i < 4; ++i) acc[i] = (f32x4){0.f, 0.f, 0.f, 0.f};

    for (int kh2 = 0; kh2 < 2; ++kh2) {
        __syncthreads();
#pragma unroll
        for (int i = 0; i < 8; ++i) {
            int lin = i * 256 + t, row = lin >> 5, c4 = lin & 31;
            float4 v = *(const float4*)&x[(rt * 64 + row) * 256 + kh2 * 128 + c4 * 4];
            ushort4 o; o.x = f2bf(v.x); o.y = f2bf(v.y); o.z = f2bf(v.z); o.w = f2bf(v.w);
            *(ushort4*)&xs[row][c4 * 4] = o;
        }
#pragma unroll
        for (int i = 0; i < 4; ++i) {
            int lin = i * 256 + t, row = lin >> 4, s = lin & 15;
            *(uint4*)&wa[row][s * 8] =
                *(const uint4*)&wt[(64 + chbase + row) * 256 + kh2 * 128 + s * 8];
        }
        __syncthreads();
#pragma unroll
        for (int kk = 0; kk < 4; ++kk) {
            bf16x8 a = *(const bf16x8*)&wa[w * 16 + n15][kk * 32 + q * 8];
#pragma unroll
            for (int nt = 0; nt < 4; ++nt) {
                bf16x8 bx = *(const bf16x8*)&xs[nt * 16 + n15][kk * 32 + q * 8];
                acc[nt] = __builtin_amdgcn_mfma_f32_16x16x32_bf16(a, bx, acc[nt], 0, 0, 0);
            }
        }
    }
#pragma unroll
    for (int nt = 0; nt < 4; ++nt)
#pragma unroll
        for (int r = 0; r < 4; ++r) {
            int ch = chbase + w * 16 + q * 4 + r;      // D row = channel
            int nloc = nbase + nt * 16 + n15;          // D col = spatial row
            hT[b * 1048576 + ch * 4096 + nloc] = f2bf(acc[nt][r]);
        }
}

// ---------------- Kernel 3: fused flash attention + residual ------------
// One WG per (batch, 64-row Q tile); 4 waves x 16 Q-rows; key tiles of 64.
__global__ __launch_bounds__(256) void k_attn(const float* __restrict__ x,
                                              const unsigned short* __restrict__ f,
                                              const unsigned short* __restrict__ g,
                                              const unsigned short* __restrict__ hT,
                                              const float* __restrict__ gamma_p,
                                              float* __restrict__ out) {
    __shared__ unsigned short gs[64][40];       // keys x 32 qk-dims (+8 pad)
    __shared__ unsigned short hs[256][72];      // channels x 64 keys (+8 pad)
    __shared__ unsigned short ps[4][16][72];    // per-wave P scratch (C->A layout)
    int t = threadIdx.x, bx = blockIdx.x;
    // XCD swizzle: blocks with same (bx&7) share an XCD; give each XCD one batch
    int b = (bx >> 1) & 3;
    int qt = ((bx & 1) << 5) | (bx >> 3);
    int qbase = qt * 64;
    int w = t >> 6, lane = t & 63, q = lane >> 4, n15 = lane & 15;

    // Q fragment (A-layout): m=lane&15 -> q-row, k=(lane>>4)*8+j
    bf16x8 aF = *(const bf16x8*)&f[(b * 4096 + qbase + w * 16 + n15) * 32 + q * 8];

    f32x4 o_acc[16];
#pragma unroll
    for (int i = 0; i < 16; ++i) o_acc[i] = (f32x4){0.f, 0.f, 0.f, 0.f};
    float m_run[4], l_run[4];
#pragma unroll
    for (int r = 0; r < 4; ++r) { m_run[r] = -1e30f; l_run[r] = 0.f; }
    const f32x4 zero4 = (f32x4){0.f, 0.f, 0.f, 0.f};

    for (int kt = 0; kt < 64; ++kt) {
        int kbase = kt * 64;
        __syncthreads();                         // prior tile fully consumed
        {   // stage G tile: 64 keys x 32 dims
            int row = t >> 2, seg = t & 3;
            *(uint4*)&gs[row][seg * 8] =
                *(const uint4*)&g[(b * 4096 + kbase + row) * 32 + seg * 8];
        }
#pragma unroll
        for (int i = 0; i < 8; ++i) {            // stage H^T tile: 256 ch x 64 keys
            int lin = i * 256 + t, ch = lin >> 3, s = lin & 7;
            *(uint4*)&hs[ch][s * 8] =
                *(const uint4*)&hT[b * 1048576 + ch * 4096 + kbase + s * 8];
        }
        __syncthreads();

        // S = F . G^T : 4 col-tiles of 16 keys, single K-step (c8=32)
        f32x4 s_acc[4];
#pragma unroll
        for (int nt = 0; nt < 4; ++nt) {
            bf16x8 bG = *(const bf16x8*)&gs[nt * 16 + n15][q * 8];
            s_acc[nt] = __builtin_amdgcn_mfma_f32_16x16x32_bf16(aF, bG, zero4, 0, 0, 0);
        }
        // online softmax: lane holds rows (lane>>4)*4+j across 16-lane col groups
        float rowmax[4];
#pragma unroll
        for (int j = 0; j < 4; ++j)
            rowmax[j] = fmaxf(fmaxf(s_acc[0][j], s_acc[1][j]), fmaxf(s_acc[2][j], s_acc[3][j]));
#pragma unroll
        for (int mask = 1; mask <= 8; mask <<= 1)
#pragma unroll
            for (int j = 0; j < 4; ++j)
                rowmax[j] = fmaxf(rowmax[j], __shfl_xor(rowmax[j], mask));
        float mnew[4], alpha[4], psum[4];
#pragma unroll
        for (int j = 0; j < 4; ++j) {
            mnew[j] = fmaxf(m_run[j], rowmax[j]);
            alpha[j] = __expf(m_run[j] - mnew[j]);
            psum[j] = 0.f;
        }
#pragma unroll
        for (int nt = 0; nt < 4; ++nt)
#pragma unroll
            for (int j = 0; j < 4; ++j) {
                float p = __expf(s_acc[nt][j] - mnew[j]);
                psum[j] += p;
                ps[w][q * 4 + j][nt * 16 + n15] = f2bf(p);   // C-layout -> LDS
            }
#pragma unroll
        for (int mask = 1; mask <= 8; mask <<= 1)
#pragma unroll
            for (int j = 0; j < 4; ++j) psum[j] += __shfl_xor(psum[j], mask);
#pragma unroll
        for (int j = 0; j < 4; ++j) {
            l_run[j] = l_run[j] * alpha[j] + psum[j];
            m_run[j] = mnew[j];
        }
#pragma unroll
        for (int nt2 = 0; nt2 < 16; ++nt2)
#pragma unroll
            for (int j = 0; j < 4; ++j) o_acc[nt2][j] *= alpha[j];

        // O += P . H : read P back in A-layout (same-wave DS ops are in-order)
        bf16x8 aP0 = *(const bf16x8*)&ps[w][n15][q * 8];
        bf16x8 aP1 = *(const bf16x8*)&ps[w][n15][32 + q * 8];
#pragma unroll
        for (int nt2 = 0; nt2 < 16; ++nt2) {
            bf16x8 b0 = *(const bf16x8*)&hs[nt2 * 16 + n15][q * 8];
            o_acc[nt2] = __builtin_amdgcn_mfma_f32_16x16x32_bf16(aP0, b0, o_acc[nt2], 0, 0, 0);
            bf16x8 b1 = *(const bf16x8*)&hs[nt2 * 16 + n15][32 + q * 8];
            o_acc[nt2] = __builtin_amdgcn_mfma_f32_16x16x32_bf16(aP1, b1, o_acc[nt2], 0, 0, 0);
        }
    }

    float gam = *gamma_p;
    float rinv[4];
#pragma unroll
    for (int r = 0; r < 4; ++r) rinv[r] = 1.0f / l_run[r];
#pragma unroll
    for (int nt2 = 0; nt2 < 16; ++nt2)
#pragma unroll
        for (int r = 0; r < 4; ++r) {
            int row = qbase + w * 16 + q * 4 + r;
            int ch = nt2 * 16 + n15;
            int idx = (b * 4096 + row) * 256 + ch;
            out[idx] = x[idx] + gam * (o_acc[nt2][r] * rinv[r]);
        }
}

// ---------------- launch ------------------------------------------------
extern "C" void kernel_launch(void* const* d_in, const int* in_sizes, int n_in,
                              void* d_out, int out_size, void* d_ws, size_t ws_size,
                              hipStream_t stream) {
    const float* x  = (const float*)d_in[0];
    const float* kf = (const float*)d_in[1];
    const float* kg = (const float*)d_in[2];
    const float* kh = (const float*)d_in[3];
    const float* gm = (const float*)d_in[4];
    float* out = (float*)d_out;

    char* ws = (char*)d_ws;
    unsigned short* wt = (unsigned short*)(ws);             // 320*256*2   = 163840 B
    unsigned short* fb = (unsigned short*)(ws + 163840);    // 16384*32*2  = 1 MiB
    unsigned short* gb = (unsigned short*)(ws + 1212416);   // 16384*32*2  = 1 MiB
    unsigned short* hT = (unsigned short*)(ws + 2260992);   // 4*256*4096*2= 8 MiB

    hipLaunchKernelGGL(k_wt,      dim3(320),  dim3(256), 0, stream, kf, kg, kh, wt);
    hipLaunchKernelGGL(k_proj_fg, dim3(256),  dim3(256), 0, stream, x, wt, fb, gb);
    hipLaunchKernelGGL(k_proj_h,  dim3(1024), dim3(256), 0, stream, x, wt, hT);
    hipLaunchKernelGGL(k_attn,    dim3(256),  dim3(256), 0, stream, x, fb, gb, hT, gm, out);
}

// Round 2
// 228.582 us; speedup vs baseline: 1.0544x; 1.0544x over previous
//
#include <hip/hip_runtime.h>

typedef __attribute__((ext_vector_type(8))) short bf16x8;
typedef __attribute__((ext_vector_type(4))) float f32x4;

__device__ __forceinline__ unsigned short f2bf(float f) {
    union { float f; unsigned u; } v; v.f = f;
    return (unsigned short)((v.u + 0x7FFFu + ((v.u >> 16) & 1u)) >> 16);  // RNE
}

// async global->LDS, 16B per lane, LDS dest = uniform base + lane*16
__device__ __forceinline__ void async16(unsigned short* lds, const unsigned short* gsrc) {
    __builtin_amdgcn_global_load_lds(
        (const __attribute__((address_space(1))) void*)gsrc,
        (__attribute__((address_space(3))) void*)lds, 16, 0, 0);
}

// ---------------- Kernel 0: weight transpose + bf16 cast ----------------
__global__ __launch_bounds__(256) void k_wt(const float* __restrict__ kf,
                                            const float* __restrict__ kg,
                                            const float* __restrict__ kh,
                                            unsigned short* __restrict__ wt) {
    int n = blockIdx.x, t = threadIdx.x;
    const float* src; int stride, col;
    if (n < 32)      { src = kf; stride = 32;  col = n; }
    else if (n < 64) { src = kg; stride = 32;  col = n - 32; }
    else             { src = kh; stride = 256; col = n - 64; }
    wt[n * 256 + t] = f2bf(src[t * stride + col]);
}

// ---------------- Kernel 1: fused projections (fg + h) ------------------
// blocks [0,256): f,g   M=16384,N=64,K=256
// blocks [256,1280): hT (swapped operands, D[ch][row])
__global__ __launch_bounds__(256) void k_proj(const float* __restrict__ x,
                                              const unsigned short* __restrict__ wt,
                                              unsigned short* __restrict__ f,
                                              unsigned short* __restrict__ g,
                                              unsigned short* __restrict__ hT) {
    __shared__ unsigned short s0[64][136];
    __shared__ unsigned short s1[64][136];
    int t = threadIdx.x;
    int w = t >> 6, lane = t & 63, q = lane >> 4, n15 = lane & 15;
    f32x4 acc[4];
#pragma unroll
    for (int i = 0; i < 4; ++i) acc[i] = (f32x4){0.f, 0.f, 0.f, 0.f};

    if (blockIdx.x < 256) {
        int rb = blockIdx.x;
        for (int kh2 = 0; kh2 < 2; ++kh2) {
            __syncthreads();
#pragma unroll
            for (int i = 0; i < 8; ++i) {            // x tile 64x128 -> bf16
                int lin = i * 256 + t, row = lin >> 5, c4 = lin & 31;
                float4 v = *(const float4*)&x[(rb * 64 + row) * 256 + kh2 * 128 + c4 * 4];
                ushort4 o; o.x = f2bf(v.x); o.y = f2bf(v.y); o.z = f2bf(v.z); o.w = f2bf(v.w);
                *(ushort4*)&s0[row][c4 * 4] = o;
            }
#pragma unroll
            for (int i = 0; i < 4; ++i) {            // Wt rows 0..63
                int lin = i * 256 + t, row = lin >> 4, s = lin & 15;
                *(uint4*)&s1[row][s * 8] = *(const uint4*)&wt[row * 256 + kh2 * 128 + s * 8];
            }
            __syncthreads();
#pragma unroll
            for (int kk = 0; kk < 4; ++kk) {
                bf16x8 a = *(const bf16x8*)&s0[w * 16 + n15][kk * 32 + q * 8];
#pragma unroll
                for (int nt = 0; nt < 4; ++nt) {
                    bf16x8 b = *(const bf16x8*)&s1[nt * 16 + n15][kk * 32 + q * 8];
                    acc[nt] = __builtin_amdgcn_mfma_f32_16x16x32_bf16(a, b, acc[nt], 0, 0, 0);
                }
            }
        }
#pragma unroll
        for (int nt = 0; nt < 4; ++nt)
#pragma unroll
            for (int r = 0; r < 4; ++r) {
                int grow = rb * 64 + w * 16 + q * 4 + r;
                int col = nt * 16 + n15;
                unsigned short v = f2bf(acc[nt][r]);
                if (col < 32) f[grow * 32 + col] = v;
                else          g[grow * 32 + (col - 32)] = v;
            }
    } else {
        int bid = blockIdx.x - 256;
        int ct = bid & 3, rt = bid >> 2;
        int chbase = ct * 64;
        int b = rt >> 6, nbase = (rt & 63) * 64;
        for (int kh2 = 0; kh2 < 2; ++kh2) {
            __syncthreads();
#pragma unroll
            for (int i = 0; i < 8; ++i) {
                int lin = i * 256 + t, row = lin >> 5, c4 = lin & 31;
                float4 v = *(const float4*)&x[(rt * 64 + row) * 256 + kh2 * 128 + c4 * 4];
                ushort4 o; o.x = f2bf(v.x); o.y = f2bf(v.y); o.z = f2bf(v.z); o.w = f2bf(v.w);
                *(ushort4*)&s0[row][c4 * 4] = o;
            }
#pragma unroll
            for (int i = 0; i < 4; ++i) {
                int lin = i * 256 + t, row = lin >> 4, s = lin & 15;
                *(uint4*)&s1[row][s * 8] =
                    *(const uint4*)&wt[(64 + chbase + row) * 256 + kh2 * 128 + s * 8];
            }
            __syncthreads();
#pragma unroll
            for (int kk = 0; kk < 4; ++kk) {
                bf16x8 a = *(const bf16x8*)&s1[w * 16 + n15][kk * 32 + q * 8];
#pragma unroll
                for (int nt = 0; nt < 4; ++nt) {
                    bf16x8 bx = *(const bf16x8*)&s0[nt * 16 + n15][kk * 32 + q * 8];
                    acc[nt] = __builtin_amdgcn_mfma_f32_16x16x32_bf16(a, bx, acc[nt], 0, 0, 0);
                }
            }
        }
#pragma unroll
        for (int nt = 0; nt < 4; ++nt)
#pragma unroll
            for (int r = 0; r < 4; ++r) {
                int ch = chbase + w * 16 + q * 4 + r;
                int nloc = nbase + nt * 16 + n15;
                hT[b * 1048576 + ch * 4096 + nloc] = f2bf(acc[nt][r]);
            }
    }
}

// ---------------- Kernel 2: fused flash attention + residual ------------
// One WG per (batch, 64-row Q tile); 4 waves x 16 Q-rows; key tiles of 64.
// Double-buffered async staging (global_load_lds w=16), ONE barrier/iter:
//   barrier -> issue prefetch(kt+1) -> compute(kt)
// The compiler's vmcnt(0) drain at the NEXT barrier lands a full compute
// phase after issue -> latency hidden even at 1 WG/CU.
// LDS layouts are unpadded (lane->LDS mapping is fixed); bank conflicts
// avoided by XOR-swizzling the SOURCE segment index (2-way alias = free).
__global__ __launch_bounds__(256) void k_attn(const float* __restrict__ x,
                                              const unsigned short* __restrict__ f,
                                              const unsigned short* __restrict__ g,
                                              const unsigned short* __restrict__ hT,
                                              const float* __restrict__ gamma_p,
                                              float* __restrict__ out) {
    __shared__ unsigned short gs[2][64][32];    // keys x 32 qk-dims, seg-swizzled
    __shared__ unsigned short hs[2][256][64];   // ch x 64 keys, seg-swizzled
    __shared__ unsigned short ps[4][16][72];    // per-wave P scratch (padded, VGPR path)
    int t = threadIdx.x, bx = blockIdx.x;
    int b = (bx >> 1) & 3;                      // XCD swizzle: one batch per XCD
    int qt = ((bx & 1) << 5) | (bx >> 3);
    int qbase = qt * 64;
    int w = t >> 6, lane = t & 63, q = lane >> 4, n15 = lane & 15;

    // Q fragment (A-layout)
    bf16x8 aF = *(const bf16x8*)&f[(b * 4096 + qbase + w * 16 + n15) * 32 + q * 8];

    // per-lane staging source base pointers (swizzled segment baked in)
    // hs: instr i covers ch rows w*64+i*8 .. +8; lane -> ch=+lane>>3, seg=(lane&7)^(lane>>3)
    const unsigned short* hp0 = hT + b * 1048576
        + (w * 64 + (lane >> 3)) * 4096 + (((lane & 7) ^ (lane >> 3)) << 3);
    // gs: 1 instr/wave, rows w*16..+16; lane -> row=+lane>>2, seg=(lane&3)^((lane>>3)&3)
    const unsigned short* gp0 = g + (b * 4096 + w * 16 + (lane >> 2)) * 32
        + (((lane & 3) ^ ((lane >> 3) & 3)) << 3);

    // read-side swizzled column offsets (loop-invariant)
    const int cg = (q ^ ((n15 >> 1) & 3)) * 8;  // gs B-frag
    const int c0 = (q ^ (n15 & 7)) * 8;         // hs B-frag keys 0..31
    const int c1 = c0 ^ 32;                     // hs B-frag keys 32..63

    f32x4 o_acc[16];
#pragma unroll
    for (int i = 0; i < 16; ++i) o_acc[i] = (f32x4){0.f, 0.f, 0.f, 0.f};
    float m_run[4], l_run[4];
#pragma unroll
    for (int r = 0; r < 4; ++r) { m_run[r] = -1e30f; l_run[r] = 0.f; }
    const f32x4 zero4 = (f32x4){0.f, 0.f, 0.f, 0.f};

    // prefetch tile 0 into buffer 0
    {
#pragma unroll
        for (int i = 0; i < 8; ++i)
            async16(&hs[0][w * 64 + i * 8][0], hp0 + i * 8 * 4096);
        async16(&gs[0][w * 16][0], gp0);
    }

    for (int kt = 0; kt < 64; ++kt) {
        int cur = kt & 1, nxt = cur ^ 1;
        __syncthreads();   // drains prefetch(kt) [vmcnt0 before s_barrier] + guards buf reuse

        if (kt + 1 < 64) { // issue prefetch(kt+1) FIRST so it flies during compute
            const unsigned short* hp = hp0 + (kt + 1) * 64;
            const unsigned short* gp = gp0 + (kt + 1) * 2048;
#pragma unroll
            for (int i = 0; i < 8; ++i)
                async16(&hs[nxt][w * 64 + i * 8][0], hp + i * 8 * 4096);
            async16(&gs[nxt][w * 16][0], gp);
        }

        // S = F . G^T
        f32x4 s_acc[4];
#pragma unroll
        for (int nt = 0; nt < 4; ++nt) {
            bf16x8 bG = *(const bf16x8*)&gs[cur][nt * 16 + n15][cg];
            s_acc[nt] = __builtin_amdgcn_mfma_f32_16x16x32_bf16(aF, bG, zero4, 0, 0, 0);
        }
        // online softmax (C-layout: lane owns rows q*4+j across 16-lane col groups)
        float rowmax[4];
#pragma unroll
        for (int j = 0; j < 4; ++j)
            rowmax[j] = fmaxf(fmaxf(s_acc[0][j], s_acc[1][j]), fmaxf(s_acc[2][j], s_acc[3][j]));
#pragma unroll
        for (int mask = 1; mask <= 8; mask <<= 1)
#pragma unroll
            for (int j = 0; j < 4; ++j)
                rowmax[j] = fmaxf(rowmax[j], __shfl_xor(rowmax[j], mask));
        float mnew[4], alpha[4], psum[4];
#pragma unroll
        for (int j = 0; j < 4; ++j) {
            mnew[j] = fmaxf(m_run[j], rowmax[j]);
            alpha[j] = __expf(m_run[j] - mnew[j]);
            psum[j] = 0.f;
        }
#pragma unroll
        for (int nt = 0; nt < 4; ++nt)
#pragma unroll
            for (int j = 0; j < 4; ++j) {
                float p = __expf(s_acc[nt][j] - mnew[j]);
                psum[j] += p;
                ps[w][q * 4 + j][nt * 16 + n15] = f2bf(p);   // C-layout -> LDS
            }
#pragma unroll
        for (int mask = 1; mask <= 8; mask <<= 1)
#pragma unroll
            for (int j = 0; j < 4; ++j) psum[j] += __shfl_xor(psum[j], mask);
#pragma unroll
        for (int j = 0; j < 4; ++j) {
            l_run[j] = l_run[j] * alpha[j] + psum[j];
            m_run[j] = mnew[j];
        }
#pragma unroll
        for (int nt2 = 0; nt2 < 16; ++nt2)
#pragma unroll
            for (int j = 0; j < 4; ++j) o_acc[nt2][j] *= alpha[j];

        // O += P . H  (P read back in A-layout; same-wave DS ordering)
        bf16x8 aP0 = *(const bf16x8*)&ps[w][n15][q * 8];
        bf16x8 aP1 = *(const bf16x8*)&ps[w][n15][32 + q * 8];
#pragma unroll
        for (int nt2 = 0; nt2 < 16; ++nt2) {
            bf16x8 b0 = *(const bf16x8*)&hs[cur][nt2 * 16 + n15][c0];
            o_acc[nt2] = __builtin_amdgcn_mfma_f32_16x16x32_bf16(aP0, b0, o_acc[nt2], 0, 0, 0);
            bf16x8 b1 = *(const bf16x8*)&hs[cur][nt2 * 16 + n15][c1];
            o_acc[nt2] = __builtin_amdgcn_mfma_f32_16x16x32_bf16(aP1, b1, o_acc[nt2], 0, 0, 0);
        }
    }

    float gam = *gamma_p;
    float rinv[4];
#pragma unroll
    for (int r = 0; r < 4; ++r) rinv[r] = 1.0f / l_run[r];
#pragma unroll
    for (int nt2 = 0; nt2 < 16; ++nt2)
#pragma unroll
        for (int r = 0; r < 4; ++r) {
            int row = qbase + w * 16 + q * 4 + r;
            int ch = nt2 * 16 + n15;
            int idx = (b * 4096 + row) * 256 + ch;
            out[idx] = x[idx] + gam * (o_acc[nt2][r] * rinv[r]);
        }
}

// ---------------- launch ------------------------------------------------
extern "C" void kernel_launch(void* const* d_in, const int* in_sizes, int n_in,
                              void* d_out, int out_size, void* d_ws, size_t ws_size,
                              hipStream_t stream) {
    const float* x  = (const float*)d_in[0];
    const float* kf = (const float*)d_in[1];
    const float* kg = (const float*)d_in[2];
    const float* kh = (const float*)d_in[3];
    const float* gm = (const float*)d_in[4];
    float* out = (float*)d_out;

    char* ws = (char*)d_ws;
    unsigned short* wt = (unsigned short*)(ws);             // 320*256*2   = 163840 B
    unsigned short* fb = (unsigned short*)(ws + 163840);    // 16384*32*2  = 1 MiB
    unsigned short* gb = (unsigned short*)(ws + 1212416);   // 16384*32*2  = 1 MiB
    unsigned short* hT = (unsigned short*)(ws + 2260992);   // 4*256*4096*2= 8 MiB

    hipLaunchKernelGGL(k_wt,   dim3(320),  dim3(256), 0, stream, kf, kg, kh, wt);
    hipLaunchKernelGGL(k_proj, dim3(1280), dim3(256), 0, stream, x, wt, fb, gb, hT);
    hipLaunchKernelGGL(k_attn, dim3(256),  dim3(256), 0, stream, x, fb, gb, hT, gm, out);
}